// Round 6
// baseline (259.567 us; speedup 1.0000x reference)
//
#include <hip/hip_runtime.h>
#include <hip/hip_bf16.h>

#define N_NODES 50000
#define K_NB 16
#define E_EDGES 800000
#define B_MOL 1024
#define MAXM_M 48
#define FDIM 9
#define ADIM 10
#define H 64
#define NEG_INF_F (-1e9f)
#define PRE_NODE_BLOCKS 196  /* 1 thread per node */
#define EDGE_BLOCKS 3125     /* 256 edges per block */
#define GAT2_NB 3126         /* (N_NODES+16)/16 */
#define ROW_SPLIT 25000      /* phase0: rows [0,25000); phase1: [25000,50001) */

typedef __bf16 bf16x8 __attribute__((ext_vector_type(8)));
typedef float f32x4 __attribute__((ext_vector_type(4)));
typedef float f32x2 __attribute__((ext_vector_type(2)));

__device__ inline float readlane_f(float v, int l) {
    return __int_as_float(__builtin_amdgcn_readlane(__float_as_int(v), l));
}
__device__ inline int readlane_i(int v, int l) {
    return __builtin_amdgcn_readlane(v, l);
}
__device__ inline float bf2f(unsigned u) {         // u = zero-extended bf16
    return __uint_as_float(u << 16);
}
__device__ inline unsigned short f2bf(float f) {   // round-to-nearest-even
    unsigned x = __float_as_uint(f);
    return (unsigned short)((x + 0x7fffu + ((x >> 16) & 1u)) >> 16);
}

// Raw gather, wave-uniform SGPR base + per-lane VGPR byte offset.
#define GLOAD_U16(dst, voff, sbase) \
    asm volatile("global_load_ushort %0, %1, %2" : "=v"(dst) : "v"(voff), "s"(sbase))
#define GLOAD_F32X2(dst, voff, sbase) \
    asm volatile("global_load_dwordx2 %0, %1, %2" : "=v"(dst) : "v"(voff), "s"(sbase))

#define DRAIN16(a) \
    asm volatile("s_waitcnt vmcnt(0)" \
        : "+v"(a[0]), "+v"(a[1]), "+v"(a[2]), "+v"(a[3]), \
          "+v"(a[4]), "+v"(a[5]), "+v"(a[6]), "+v"(a[7]), \
          "+v"(a[8]), "+v"(a[9]), "+v"(a[10]), "+v"(a[11]), \
          "+v"(a[12]), "+v"(a[13]), "+v"(a[14]), "+v"(a[15]))
#define HOLD16(a) \
    asm volatile("" \
        : "+v"(a[0]), "+v"(a[1]), "+v"(a[2]), "+v"(a[3]), \
          "+v"(a[4]), "+v"(a[5]), "+v"(a[6]), "+v"(a[7]), \
          "+v"(a[8]), "+v"(a[9]), "+v"(a[10]), "+v"(a[11]), \
          "+v"(a[12]), "+v"(a[13]), "+v"(a[14]), "+v"(a[15]))
#define HOLD16R(a, base) \
    asm volatile("" \
        : "+v"(a[base + 0]), "+v"(a[base + 1]), "+v"(a[base + 2]), "+v"(a[base + 3]), \
          "+v"(a[base + 4]), "+v"(a[base + 5]), "+v"(a[base + 6]), "+v"(a[base + 7]), \
          "+v"(a[base + 8]), "+v"(a[base + 9]), "+v"(a[base + 10]), "+v"(a[base + 11]), \
          "+v"(a[base + 12]), "+v"(a[base + 13]), "+v"(a[base + 14]), "+v"(a[base + 15]))

// ---------------------------------------------------------------------------
// Fold all weight algebra (single block) — round-0-verified version:
//   va/vb, W2/c2, W3/c3, wa/ca, wv9/cv, plus
//   WintT[64][128] bf16: WintT[n][2j]=W_gat[j][n], WintT[n][2j+1]=Wm_gat[j][n]
// ---------------------------------------------------------------------------
__global__ __launch_bounds__(256) void k_fold(
    const float* __restrict__ W_emb, const float* __restrict__ b_emb,
    const float* __restrict__ W_dist, const float* __restrict__ b_dist,
    const float* __restrict__ W_gat, const float* __restrict__ Wm_gat,
    const float* __restrict__ a_gat,
    float* __restrict__ W2, float* __restrict__ c2,
    float* __restrict__ W3, float* __restrict__ c3,
    float* __restrict__ wa, float* __restrict__ ca,
    float* __restrict__ va, float* __restrict__ vb,
    float* __restrict__ wv9, float* __restrict__ cv,
    unsigned short* __restrict__ WintT)
{
    __shared__ float s_va[64], s_vb[64];
    int tid = threadIdx.x;
    int h = tid & 63, g = tid >> 6;
    if (g == 0) {            // va[h] = W_gat[h,:] . a1
        float acc = 0.f;
        for (int t = 0; t < H; ++t) acc += W_gat[h * H + t] * a_gat[t];
        s_va[h] = acc; va[h] = acc;
    } else if (g == 1) {     // vb[h] = Wm_gat[h,:] . a2
        float acc = 0.f;
        for (int t = 0; t < H; ++t) acc += Wm_gat[h * H + t] * a_gat[H + t];
        s_vb[h] = acc; vb[h] = acc;
    } else if (g == 2) {     // c2
        float acc = 0.f;
        for (int t = 0; t < H; ++t) acc += b_dist[t] * Wm_gat[t * H + h];
        c2[h] = acc;
    } else {                 // c3
        float acc = 0.f;
        for (int t = 0; t < H; ++t) acc += b_emb[t] * W_gat[t * H + h];
        c3[h] = acc;
    }
    __syncthreads();
    for (int q = tid; q < 640; q += 256) {   // W2[j,h]
        int j = q >> 6, hh = q & 63;
        float acc = 0.f;
        for (int t = 0; t < H; ++t) acc += W_dist[j * H + t] * Wm_gat[t * H + hh];
        W2[q] = acc;
    }
    for (int q = tid; q < 576; q += 256) {   // W3[j,h]
        int j = q >> 6, hh = q & 63;
        float acc = 0.f;
        for (int t = 0; t < H; ++t) acc += W_emb[j * H + t] * W_gat[t * H + hh];
        W3[q] = acc;
    }
    for (int q = tid; q < H * 2 * H; q += 256) {  // WintT[n][k], 8192 entries
        int n = q >> 7, k = q & 127;
        float v = (k & 1) ? Wm_gat[(k >> 1) * H + n] : W_gat[(k >> 1) * H + n];
        WintT[q] = f2bf(v);
    }
    if (tid < ADIM) {                         // wa
        float acc = 0.f;
        for (int t = 0; t < H; ++t) acc += W_dist[tid * H + t] * s_vb[t];
        wa[tid] = acc;
    } else if (tid == ADIM) {                 // ca
        float acc = 0.f;
        for (int t = 0; t < H; ++t) acc += b_dist[t] * s_vb[t];
        ca[0] = acc;
    } else if (tid >= 16 && tid < 16 + FDIM) {// wv9
        int j = tid - 16;
        float acc = 0.f;
        for (int t = 0; t < H; ++t) acc += W_emb[j * H + t] * s_va[t];
        wv9[j] = acc;
    } else if (tid == 31) {                   // cv
        float acc = 0.f;
        for (int t = 0; t < H; ++t) acc += b_emb[t] * s_va[t];
        cv[0] = acc;
    }
}

// ---------------------------------------------------------------------------
// Pre-pass: t1A + tfp records (node side); emsg records (edge side).
// ---------------------------------------------------------------------------
__global__ __launch_bounds__(256) void k_pre(
    const float* __restrict__ tf, const float* __restrict__ fdg,
    const float* __restrict__ rij,
    const float* __restrict__ wa, const float* __restrict__ ca,
    const float* __restrict__ wv9, const float* __restrict__ cv,
    float* __restrict__ t1A, unsigned short* __restrict__ tfp,
    unsigned short* __restrict__ emsg)
{
    int bid = blockIdx.x;
    if (bid < PRE_NODE_BLOCKS) {
        int n = bid * 256 + threadIdx.x;
        if (n == 0) {                        // zero pad row
            t1A[0] = 0.f;
            uint4 z = make_uint4(0, 0, 0, 0);
            ((uint4*)tfp)[0] = z; ((uint4*)tfp)[1] = z;
        }
        if (n >= N_NODES) return;
        float f[FDIM];
        float acc = cv[0];
#pragma unroll
        for (int j = 0; j < FDIM; ++j) {
            f[j] = tf[n * FDIM + j];
            acc += f[j] * wv9[j];
        }
        t1A[n + 1] = acc;
        unsigned rec[8];
#pragma unroll
        for (int j = 0; j < 4; ++j)
            rec[j] = (unsigned)f2bf(f[2 * j]) | ((unsigned)f2bf(f[2 * j + 1]) << 16);
        rec[4] = (unsigned)f2bf(f[8]);
        rec[5] = 0; rec[6] = 0; rec[7] = 0;
        uint4* dst = (uint4*)(tfp + (size_t)(n + 1) * 16);
        dst[0] = make_uint4(rec[0], rec[1], rec[2], rec[3]);
        dst[1] = make_uint4(rec[4], rec[5], rec[6], rec[7]);
    } else {
        int e = (bid - PRE_NODE_BLOCKS) * 256 + threadIdx.x;
        float f[ADIM];
#pragma unroll
        for (int j = 0; j < FDIM; ++j) f[j] = fdg[(size_t)e * FDIM + j];
        f[FDIM] = rij[e];
        float acc = ca[0];
#pragma unroll
        for (int j = 0; j < ADIM; ++j) acc += f[j] * wa[j];
        unsigned rec[8];
#pragma unroll
        for (int j = 0; j < 5; ++j)
            rec[j] = (unsigned)f2bf(f[2 * j]) | ((unsigned)f2bf(f[2 * j + 1]) << 16);
        rec[5] = __float_as_uint(acc);
        rec[6] = 0; rec[7] = 0;
        uint4* dst = (uint4*)(emsg + (size_t)e * 16);
        dst[0] = make_uint4(rec[0], rec[1], rec[2], rec[3]);
        dst[1] = make_uint4(rec[4], rec[5], rec[6], rec[7]);
    }
}

// ---------------------------------------------------------------------------
// ksu_nk[n][k] = sul[e]>0 ? su[e] : 0, e=bsc[n][k]  (random sue gather
// hoisted out of k_gat2; values provably identical to round-0's sue[ke]).
// ---------------------------------------------------------------------------
__global__ __launch_bounds__(256) void k_ksu(
    const int* __restrict__ bsc, const int* __restrict__ su,
    const int* __restrict__ sul, int* __restrict__ ksu_nk)
{
    int i = blockIdx.x * 256 + threadIdx.x;   // 3125*256 == 800000 exact
    int e = bsc[i];
    ksu_nk[i] = (sul[e] > 0) ? su[e] : 0;
}

// ---------------------------------------------------------------------------
// GAT iter 1 (round-10 shape, measured 42us). One wave per node.
// ---------------------------------------------------------------------------
__global__ __launch_bounds__(256) void k_gat1(
    const int* __restrict__ sse, const int* __restrict__ bsc,
    const float* __restrict__ t1A, const unsigned short* __restrict__ tfp,
    const unsigned short* __restrict__ emsg,
    const float* __restrict__ W2, const float* __restrict__ c2,
    const float* __restrict__ W3, const float* __restrict__ c3,
    const float* __restrict__ va, const float* __restrict__ vb,
    unsigned short* __restrict__ hp2bf, float* __restrict__ t1B,
    float* __restrict__ t2B)
{
    int wave = threadIdx.x >> 6;
    int lane = threadIdx.x & 63;
    int n = blockIdx.x * 4 + wave;
    if (n == 0) {
        hp2bf[lane] = 0;
        if (lane == 0) { t1B[0] = 0.f; t2B[0] = 0.f; }
    }
    if (n >= N_NODES) return;

    int kidx = 0, ke = 0;
    float lg = NEG_INF_F;
    if (lane < K_NB) {
        kidx = sse[n * K_NB + lane];
        ke   = bsc[n * K_NB + lane];
        float g2 = __uint_as_float(*(const unsigned*)(emsg + (size_t)ke * 16 + 10));
        float p = t1A[kidx] + g2;
        p = (p > 0.f) ? p : 0.2f * p;      // leaky_relu(0.2)
        lg = (kidx == 0) ? NEG_INF_F : p;  // pad mask
    }

    unsigned wn_u[K_NB], wm_u[K_NB];
    int offr = (lane & 15) * 2;            // short index within 32B record
#pragma unroll
    for (int k = 0; k < K_NB; ++k) {
        const unsigned short* pk = tfp + (size_t)readlane_i(kidx, k) * 16;
        GLOAD_U16(wn_u[k], offr, pk);
    }
#pragma unroll
    for (int k = 0; k < K_NB; ++k) {
        const unsigned short* pe = emsg + (size_t)readlane_i(ke, k) * 16;
        GLOAD_U16(wm_u[k], offr, pe);
    }

    // softmax across the 16-lane group — overlaps the gathers
    float m = lg;
#pragma unroll
    for (int o = 8; o > 0; o >>= 1) m = fmaxf(m, __shfl_xor(m, o, 64));
    float ex = __expf(lg - m);
    float s = ex;
#pragma unroll
    for (int o = 8; o > 0; o >>= 1) s += __shfl_xor(s, o, 64);
    float alpha = ex / s;

    DRAIN16(wn_u);
    HOLD16(wm_u);

    float fr = 0.f, frm = 0.f, beta = 0.f;
#pragma unroll
    for (int k = 0; k < K_NB; ++k) {
        float ak = readlane_f(alpha, k);
        fr  += ak * bf2f(wn_u[k]);         // lanes 9..15 read record pad zeros
        frm += ak * bf2f(wm_u[k]);         // lanes >= ADIM garbage, never read
        beta += (readlane_i(kidx, k) > 0) ? ak : 0.f;
    }
    float acc = c2[lane] + beta * c3[lane];
#pragma unroll
    for (int j = 0; j < FDIM; ++j) acc += readlane_f(fr, j) * W3[j * H + lane];
#pragma unroll
    for (int j = 0; j < ADIM; ++j) acc += readlane_f(frm, j) * W2[j * H + lane];
    float o = (acc > 0.f) ? acc : expm1f(acc);   // elu
    hp2bf[(size_t)(n + 1) * H + lane] = f2bf(o);
    float ta = o * va[lane], tb = o * vb[lane];  // f32-exact logit scalars
#pragma unroll
    for (int q = 32; q > 0; q >>= 1) {
        ta += __shfl_xor(ta, q, 64);
        tb += __shfl_xor(tb, q, 64);
    }
    if (lane == 0) { t1B[n + 1] = ta; t2B[n + 1] = tb; }
}

// ---------------------------------------------------------------------------
// GAT iter 2 — two-phase row-split for L2 residency. ROUND-6: single output
// buffer hp3pp[(row-1)*128 + col*2 + phase] (f32, phase-interleaved, pad row
// dropped) = 25,600,000 B EXACTLY aliasing emsg — workspace footprint is
// byte-identical to the round-1 PASSING kernel (overflow suspect eliminated).
// GEMM is the round-0-verified K=128 WintT form; partials stored raw f32
// (better precision than any bf16 partial scheme); elu applied in k_out.
// ---------------------------------------------------------------------------
__global__ __launch_bounds__(1024) void k_gat2(
    const int* __restrict__ sse, const int* __restrict__ ksu_nk,
    const float* __restrict__ t1B, const float* __restrict__ t2B,
    const unsigned short* __restrict__ hp2bf,
    const unsigned short* __restrict__ WintT,
    float* __restrict__ hp3pp)
{
    __shared__ unsigned s_rows[16][72];    // 16 rows x 64 uints (stride 72)
    int bid  = blockIdx.x;
    int phase = (bid >= GAT2_NB) ? 1 : 0;
    int nb   = bid - phase * GAT2_NB;
    int lo   = phase ? ROW_SPLIT : 0;
    int hi   = phase ? (N_NODES + 1) : ROW_SPLIT;
    int wave = threadIdx.x >> 6;           // 0..15 = row within block
    int lane = threadIdx.x & 63;
    int row  = nb * 16 + wave;             // hp3 row
    int n    = row - 1;                    // node index (row 0 = pad)

    float gn = 0.f, gm = 0.f;
    if (n >= 0 && n < N_NODES) {
        int kidx = 0, ksu = 0;
        float lg = NEG_INF_F;
        if (lane < K_NB) {
            kidx = sse[n * K_NB + lane];
            ksu  = ksu_nk[n * K_NB + lane];  // 0 = zero row for masked edges
            float p = t1B[kidx] + t2B[ksu];
            p = (p > 0.f) ? p : 0.2f * p;
            lg = (kidx == 0) ? NEG_INF_F : p;
        }

        unsigned wn_u[K_NB], wm_u[K_NB];
        int off = lane * 2;
#pragma unroll
        for (int k = 0; k < K_NB; ++k) {
            wn_u[k] = 0u;
            int rk = readlane_i(kidx, k);    // wave-uniform -> scalar branch
            if (rk >= lo && rk < hi) {
                const unsigned short* pk = hp2bf + (size_t)rk * H;
                GLOAD_U16(wn_u[k], off, pk);
            }
        }
#pragma unroll
        for (int k = 0; k < K_NB; ++k) {
            wm_u[k] = 0u;
            int rs = readlane_i(ksu, k);
            if (rs >= lo && rs < hi) {
                const unsigned short* ps = hp2bf + (size_t)rs * H;
                GLOAD_U16(wm_u[k], off, ps);
            }
        }

        float m = lg;
#pragma unroll
        for (int o = 8; o > 0; o >>= 1) m = fmaxf(m, __shfl_xor(m, o, 64));
        float ex = __expf(lg - m);
        float s = ex;
#pragma unroll
        for (int o = 8; o > 0; o >>= 1) s += __shfl_xor(s, o, 64);
        float alpha = ex / s;

        DRAIN16(wn_u);
        HOLD16(wm_u);

#pragma unroll
        for (int k = 0; k < K_NB; ++k) {
            float ak = readlane_f(alpha, k);
            gn += ak * bf2f(wn_u[k]);      // skipped rows stayed 0
            gm += ak * bf2f(wm_u[k]);
        }
    }
    s_rows[wave][lane] = (unsigned)f2bf(gn) | ((unsigned)f2bf(gm) << 16);
    __syncthreads();

    if (wave < 4) {                        // wave t = column strip t*16..
        int t = wave;
        int m = lane & 15, q = lane >> 4;
        union UB { uint4 u; bf16x8 v; };
        bf16x8 bfr[4];
        const unsigned short* bp = WintT + (size_t)(t * 16 + m) * 128 + q * 8;
#pragma unroll
        for (int kk = 0; kk < 4; ++kk) {
            UB ub; ub.u = *(const uint4*)(bp + kk * 32);
            bfr[kk] = ub.v;
        }
        f32x4 acc = (f32x4){0.f, 0.f, 0.f, 0.f};
#pragma unroll
        for (int kk = 0; kk < 4; ++kk) {
            UB ua; ua.u = *(const uint4*)&s_rows[m][kk * 16 + q * 4];
            acc = __builtin_amdgcn_mfma_f32_16x16x32_bf16(ua.v, bfr[kk], acc, 0, 0, 0);
        }
        int row0 = nb * 16;
#pragma unroll
        for (int r = 0; r < 4; ++r) {
            int rr = row0 + q * 4 + r;
            if (rr >= 1 && rr <= N_NODES)  // pad row 0 dropped from hp3pp
                hp3pp[((size_t)(rr - 1) * H + t * 16 + m) * 2 + phase] = acc[r];
        }
    }
}

// ---------------------------------------------------------------------------
// out[b] = sum_m elu(hp3pp[idx,:,0] + hp3pp[idx,:,1]); idx==0 contributes 0
// (exact: pad row of hp3 is elu(0)=0 in the reference). 48 dwordx2 gathers.
// ---------------------------------------------------------------------------
__global__ __launch_bounds__(256) void k_out(
    const int* __restrict__ l_scope, const float* __restrict__ hp3pp,
    float* __restrict__ out)
{
    int wave = threadIdx.x >> 6;
    int lane = threadIdx.x & 63;
    int b = blockIdx.x * 4 + wave;
    if (b >= B_MOL) return;
    int idx48 = (lane < MAXM_M) ? l_scope[b * MAXM_M + lane] : 0;
    f32x2 v[MAXM_M];
    int off = lane * 8;
#pragma unroll
    for (int m = 0; m < MAXM_M; ++m) {
        v[m] = (f32x2){0.f, 0.f};
        int idx = readlane_i(idx48, m);    // wave-uniform -> scalar branch
        if (idx > 0) {
            const float* pm = hp3pp + (size_t)(idx - 1) * (H * 2);
            GLOAD_F32X2(v[m], off, pm);
        }
    }
    asm volatile("s_waitcnt vmcnt(0)"
        : "+v"(v[0]), "+v"(v[1]), "+v"(v[2]), "+v"(v[3]),
          "+v"(v[4]), "+v"(v[5]), "+v"(v[6]), "+v"(v[7]),
          "+v"(v[8]), "+v"(v[9]), "+v"(v[10]), "+v"(v[11]),
          "+v"(v[12]), "+v"(v[13]), "+v"(v[14]), "+v"(v[15]));
    asm volatile(""
        : "+v"(v[16]), "+v"(v[17]), "+v"(v[18]), "+v"(v[19]),
          "+v"(v[20]), "+v"(v[21]), "+v"(v[22]), "+v"(v[23]),
          "+v"(v[24]), "+v"(v[25]), "+v"(v[26]), "+v"(v[27]),
          "+v"(v[28]), "+v"(v[29]), "+v"(v[30]), "+v"(v[31]));
    asm volatile(""
        : "+v"(v[32]), "+v"(v[33]), "+v"(v[34]), "+v"(v[35]),
          "+v"(v[36]), "+v"(v[37]), "+v"(v[38]), "+v"(v[39]),
          "+v"(v[40]), "+v"(v[41]), "+v"(v[42]), "+v"(v[43]),
          "+v"(v[44]), "+v"(v[45]), "+v"(v[46]), "+v"(v[47]));
    float acc = 0.f;
#pragma unroll
    for (int m = 0; m < MAXM_M; ++m) {
        float w = v[m][0] + v[m][1];       // phase0 + phase1 partials (f32)
        acc += (w > 0.f) ? w : expm1f(w);  // elu over combined partials
    }
    out[b * H + lane] = acc;
}

extern "C" void kernel_launch(void* const* d_in, const int* in_sizes, int n_in,
                              void* d_out, int out_size, void* d_ws, size_t ws_size,
                              hipStream_t stream)
{
    const float* tf     = (const float*)d_in[0];
    const float* fdg    = (const float*)d_in[1];
    const float* rij    = (const float*)d_in[2];
    const int*   sse    = (const int*)d_in[3];
    const int*   bsc    = (const int*)d_in[4];
    const int*   lsc    = (const int*)d_in[5];
    const int*   su     = (const int*)d_in[6];
    const int*   sul    = (const int*)d_in[7];
    const float* W_emb  = (const float*)d_in[8];
    const float* b_emb  = (const float*)d_in[9];
    const float* W_dist = (const float*)d_in[10];
    const float* b_dist = (const float*)d_in[11];
    const float* W_gat  = (const float*)d_in[12];
    const float* Wm_gat = (const float*)d_in[13];
    const float* a_gat  = (const float*)d_in[14];
    float* out = (float*)d_out;

    // Allocation list is BYTE-IDENTICAL to the round-1 passing kernel
    // (ksu_nk occupies the old sue slot; big is exactly E_EDGES*32).
    char* base = (char*)d_ws;
    size_t off = 0;
    auto alloc = [&](size_t bytes) {
        char* p = base + off;
        off = (off + bytes + 255) & ~(size_t)255;
        return p;
    };
    float* W2   = (float*)alloc(640 * 4);
    float* c2   = (float*)alloc(64 * 4);
    float* W3   = (float*)alloc(640 * 4);
    float* c3   = (float*)alloc(64 * 4);
    float* wa   = (float*)alloc(16 * 4);
    float* ca   = (float*)alloc(16 * 4);
    float* va   = (float*)alloc(64 * 4);
    float* vb   = (float*)alloc(64 * 4);
    float* wv9  = (float*)alloc(16 * 4);
    float* cv   = (float*)alloc(16 * 4);
    unsigned short* WintT = (unsigned short*)alloc(64 * 128 * 2);
    float* t1A  = (float*)alloc((size_t)(N_NODES + 1) * 4);
    float* t1B  = (float*)alloc((size_t)(N_NODES + 1) * 4);
    float* t2B  = (float*)alloc((size_t)(N_NODES + 1) * 4);
    int*   ksu_nk = (int*)alloc((size_t)E_EDGES * 4);
    unsigned short* tfp   = (unsigned short*)alloc((size_t)(N_NODES + 1) * 16 * 2);
    unsigned short* hp2bf = (unsigned short*)alloc((size_t)(N_NODES + 1) * H * 2);
    // emsg (25.6MB) aliases hp3pp (50000*64*2*4 = 25,600,000 B exactly):
    // emsg dead before k_gat2 writes hp3pp.
    char* big = alloc((size_t)E_EDGES * 32);
    unsigned short* emsg = (unsigned short*)big;
    float* hp3pp = (float*)big;

    k_fold<<<dim3(1), dim3(256), 0, stream>>>(
        W_emb, b_emb, W_dist, b_dist, W_gat, Wm_gat, a_gat,
        W2, c2, W3, c3, wa, ca, va, vb, wv9, cv, WintT);

    k_pre<<<dim3(PRE_NODE_BLOCKS + EDGE_BLOCKS), dim3(256), 0, stream>>>(
        tf, fdg, rij, wa, ca, wv9, cv, t1A, tfp, emsg);

    k_ksu<<<dim3(EDGE_BLOCKS), dim3(256), 0, stream>>>(bsc, su, sul, ksu_nk);

    k_gat1<<<dim3((N_NODES + 3) / 4), dim3(256), 0, stream>>>(
        sse, bsc, t1A, tfp, emsg, W2, c2, W3, c3, va, vb, hp2bf, t1B, t2B);

    k_gat2<<<dim3(2 * GAT2_NB), dim3(1024), 0, stream>>>(
        sse, ksu_nk, t1B, t2B, hp2bf, WintT, hp3pp);

    k_out<<<dim3(B_MOL / 4), dim3(256), 0, stream>>>(lsc, hp3pp, out);
}

// Round 7
// 208.178 us; speedup vs baseline: 1.2468x; 1.2468x over previous
//
#include <hip/hip_runtime.h>
#include <hip/hip_bf16.h>

#define N_NODES 50000
#define K_NB 16
#define E_EDGES 800000
#define B_MOL 1024
#define MAXM_M 48
#define FDIM 9
#define ADIM 10
#define H 64
#define NEG_INF_F (-1e9f)
#define PRE_NODE_BLOCKS 196  /* 1 thread per node */
#define EDGE_BLOCKS 3125     /* 256 edges per block */

typedef __bf16 bf16x8 __attribute__((ext_vector_type(8)));
typedef float f32x4 __attribute__((ext_vector_type(4)));

__device__ inline float readlane_f(float v, int l) {
    return __int_as_float(__builtin_amdgcn_readlane(__float_as_int(v), l));
}
__device__ inline int readlane_i(int v, int l) {
    return __builtin_amdgcn_readlane(v, l);
}
__device__ inline float bf2f(unsigned u) {         // u = zero-extended bf16
    return __uint_as_float(u << 16);
}
__device__ inline unsigned short f2bf(float f) {   // round-to-nearest-even
    unsigned x = __float_as_uint(f);
    return (unsigned short)((x + 0x7fffu + ((x >> 16) & 1u)) >> 16);
}

// Raw gather, wave-uniform SGPR base + per-lane VGPR byte offset.
#define GLOAD_U16(dst, voff, sbase) \
    asm volatile("global_load_ushort %0, %1, %2" : "=v"(dst) : "v"(voff), "s"(sbase))
#define GLOAD_F32(dst, voff, sbase) \
    asm volatile("global_load_dword %0, %1, %2" : "=v"(dst) : "v"(voff), "s"(sbase))
#define GLOAD_DW(dst, voff, sbase) \
    asm volatile("global_load_dword %0, %1, %2" : "=v"(dst) : "v"(voff), "s"(sbase))

#define DRAIN16(a) \
    asm volatile("s_waitcnt vmcnt(0)" \
        : "+v"(a[0]), "+v"(a[1]), "+v"(a[2]), "+v"(a[3]), \
          "+v"(a[4]), "+v"(a[5]), "+v"(a[6]), "+v"(a[7]), \
          "+v"(a[8]), "+v"(a[9]), "+v"(a[10]), "+v"(a[11]), \
          "+v"(a[12]), "+v"(a[13]), "+v"(a[14]), "+v"(a[15]))
#define HOLD16(a) \
    asm volatile("" \
        : "+v"(a[0]), "+v"(a[1]), "+v"(a[2]), "+v"(a[3]), \
          "+v"(a[4]), "+v"(a[5]), "+v"(a[6]), "+v"(a[7]), \
          "+v"(a[8]), "+v"(a[9]), "+v"(a[10]), "+v"(a[11]), \
          "+v"(a[12]), "+v"(a[13]), "+v"(a[14]), "+v"(a[15]))

// ---------------------------------------------------------------------------
// Fold all weight algebra (single block):
//   va/vb, W2/c2, W3/c3, wa/ca, wv9/cv, plus
//   WintT[64][128] bf16: WintT[n][2j]=W_gat[j][n], WintT[n][2j+1]=Wm_gat[j][n]
// ---------------------------------------------------------------------------
__global__ __launch_bounds__(256) void k_fold(
    const float* __restrict__ W_emb, const float* __restrict__ b_emb,
    const float* __restrict__ W_dist, const float* __restrict__ b_dist,
    const float* __restrict__ W_gat, const float* __restrict__ Wm_gat,
    const float* __restrict__ a_gat,
    float* __restrict__ W2, float* __restrict__ c2,
    float* __restrict__ W3, float* __restrict__ c3,
    float* __restrict__ wa, float* __restrict__ ca,
    float* __restrict__ va, float* __restrict__ vb,
    float* __restrict__ wv9, float* __restrict__ cv,
    unsigned short* __restrict__ WintT)
{
    __shared__ float s_va[64], s_vb[64];
    int tid = threadIdx.x;
    int h = tid & 63, g = tid >> 6;
    if (g == 0) {            // va[h] = W_gat[h,:] . a1
        float acc = 0.f;
        for (int t = 0; t < H; ++t) acc += W_gat[h * H + t] * a_gat[t];
        s_va[h] = acc; va[h] = acc;
    } else if (g == 1) {     // vb[h] = Wm_gat[h,:] . a2
        float acc = 0.f;
        for (int t = 0; t < H; ++t) acc += Wm_gat[h * H + t] * a_gat[H + t];
        s_vb[h] = acc; vb[h] = acc;
    } else if (g == 2) {     // c2
        float acc = 0.f;
        for (int t = 0; t < H; ++t) acc += b_dist[t] * Wm_gat[t * H + h];
        c2[h] = acc;
    } else {                 // c3
        float acc = 0.f;
        for (int t = 0; t < H; ++t) acc += b_emb[t] * W_gat[t * H + h];
        c3[h] = acc;
    }
    __syncthreads();
    for (int q = tid; q < 640; q += 256) {   // W2[j,h]
        int j = q >> 6, hh = q & 63;
        float acc = 0.f;
        for (int t = 0; t < H; ++t) acc += W_dist[j * H + t] * Wm_gat[t * H + hh];
        W2[q] = acc;
    }
    for (int q = tid; q < 576; q += 256) {   // W3[j,h]
        int j = q >> 6, hh = q & 63;
        float acc = 0.f;
        for (int t = 0; t < H; ++t) acc += W_emb[j * H + t] * W_gat[t * H + hh];
        W3[q] = acc;
    }
    for (int q = tid; q < H * 2 * H; q += 256) {  // WintT[n][k], 8192 entries
        int n = q >> 7, k = q & 127;
        float v = (k & 1) ? Wm_gat[(k >> 1) * H + n] : W_gat[(k >> 1) * H + n];
        WintT[q] = f2bf(v);
    }
    if (tid < ADIM) {                         // wa
        float acc = 0.f;
        for (int t = 0; t < H; ++t) acc += W_dist[tid * H + t] * s_vb[t];
        wa[tid] = acc;
    } else if (tid == ADIM) {                 // ca
        float acc = 0.f;
        for (int t = 0; t < H; ++t) acc += b_dist[t] * s_vb[t];
        ca[0] = acc;
    } else if (tid >= 16 && tid < 16 + FDIM) {// wv9
        int j = tid - 16;
        float acc = 0.f;
        for (int t = 0; t < H; ++t) acc += W_emb[j * H + t] * s_va[t];
        wv9[j] = acc;
    } else if (tid == 31) {                   // cv
        float acc = 0.f;
        for (int t = 0; t < H; ++t) acc += b_emb[t] * s_va[t];
        cv[0] = acc;
    }
}

// ---------------------------------------------------------------------------
// Pre-pass: t1A + tfp records (node side); emsg records + sue (edge side).
// ---------------------------------------------------------------------------
__global__ __launch_bounds__(256) void k_pre(
    const float* __restrict__ tf, const float* __restrict__ fdg,
    const float* __restrict__ rij,
    const int* __restrict__ su, const int* __restrict__ sul,
    const float* __restrict__ wa, const float* __restrict__ ca,
    const float* __restrict__ wv9, const float* __restrict__ cv,
    float* __restrict__ t1A, unsigned short* __restrict__ tfp,
    unsigned short* __restrict__ emsg, int* __restrict__ sue)
{
    int bid = blockIdx.x;
    if (bid < PRE_NODE_BLOCKS) {
        int n = bid * 256 + threadIdx.x;
        if (n == 0) {                        // zero pad row
            t1A[0] = 0.f;
            uint4 z = make_uint4(0, 0, 0, 0);
            ((uint4*)tfp)[0] = z; ((uint4*)tfp)[1] = z;
        }
        if (n >= N_NODES) return;
        float f[FDIM];
        float acc = cv[0];
#pragma unroll
        for (int j = 0; j < FDIM; ++j) {
            f[j] = tf[n * FDIM + j];
            acc += f[j] * wv9[j];
        }
        t1A[n + 1] = acc;
        unsigned rec[8];
#pragma unroll
        for (int j = 0; j < 4; ++j)
            rec[j] = (unsigned)f2bf(f[2 * j]) | ((unsigned)f2bf(f[2 * j + 1]) << 16);
        rec[4] = (unsigned)f2bf(f[8]);
        rec[5] = 0; rec[6] = 0; rec[7] = 0;
        uint4* dst = (uint4*)(tfp + (size_t)(n + 1) * 16);
        dst[0] = make_uint4(rec[0], rec[1], rec[2], rec[3]);
        dst[1] = make_uint4(rec[4], rec[5], rec[6], rec[7]);
    } else {
        int e = (bid - PRE_NODE_BLOCKS) * 256 + threadIdx.x;
        float f[ADIM];
#pragma unroll
        for (int j = 0; j < FDIM; ++j) f[j] = fdg[(size_t)e * FDIM + j];
        f[FDIM] = rij[e];
        float acc = ca[0];
#pragma unroll
        for (int j = 0; j < ADIM; ++j) acc += f[j] * wa[j];
        unsigned rec[8];
#pragma unroll
        for (int j = 0; j < 5; ++j)
            rec[j] = (unsigned)f2bf(f[2 * j]) | ((unsigned)f2bf(f[2 * j + 1]) << 16);
        rec[5] = __float_as_uint(acc);
        rec[6] = 0; rec[7] = 0;
        uint4* dst = (uint4*)(emsg + (size_t)e * 16);
        dst[0] = make_uint4(rec[0], rec[1], rec[2], rec[3]);
        dst[1] = make_uint4(rec[4], rec[5], rec[6], rec[7]);
        sue[e] = (sul[e] > 0) ? su[e] : 0;
    }
}

// ---------------------------------------------------------------------------
// GAT iter 1 (round-10 shape, measured 42us). One wave per node.
// ---------------------------------------------------------------------------
__global__ __launch_bounds__(256) void k_gat1(
    const int* __restrict__ sse, const int* __restrict__ bsc,
    const float* __restrict__ t1A, const unsigned short* __restrict__ tfp,
    const unsigned short* __restrict__ emsg,
    const float* __restrict__ W2, const float* __restrict__ c2,
    const float* __restrict__ W3, const float* __restrict__ c3,
    const float* __restrict__ va, const float* __restrict__ vb,
    unsigned short* __restrict__ hp2bf, float* __restrict__ t1B,
    float* __restrict__ t2B)
{
    int wave = threadIdx.x >> 6;
    int lane = threadIdx.x & 63;
    int n = blockIdx.x * 4 + wave;
    if (n == 0) {
        hp2bf[lane] = 0;
        if (lane == 0) { t1B[0] = 0.f; t2B[0] = 0.f; }
    }
    if (n >= N_NODES) return;

    int kidx = 0, ke = 0;
    float lg = NEG_INF_F;
    if (lane < K_NB) {
        kidx = sse[n * K_NB + lane];
        ke   = bsc[n * K_NB + lane];
        float g2 = __uint_as_float(*(const unsigned*)(emsg + (size_t)ke * 16 + 10));
        float p = t1A[kidx] + g2;
        p = (p > 0.f) ? p : 0.2f * p;      // leaky_relu(0.2)
        lg = (kidx == 0) ? NEG_INF_F : p;  // pad mask
    }

    unsigned wn_u[K_NB], wm_u[K_NB];
    int offr = (lane & 15) * 2;            // short index within 32B record
#pragma unroll
    for (int k = 0; k < K_NB; ++k) {
        const unsigned short* pk = tfp + (size_t)readlane_i(kidx, k) * 16;
        GLOAD_U16(wn_u[k], offr, pk);
    }
#pragma unroll
    for (int k = 0; k < K_NB; ++k) {
        const unsigned short* pe = emsg + (size_t)readlane_i(ke, k) * 16;
        GLOAD_U16(wm_u[k], offr, pe);
    }

    // softmax across the 16-lane group — overlaps the gathers
    float m = lg;
#pragma unroll
    for (int o = 8; o > 0; o >>= 1) m = fmaxf(m, __shfl_xor(m, o, 64));
    float ex = __expf(lg - m);
    float s = ex;
#pragma unroll
    for (int o = 8; o > 0; o >>= 1) s += __shfl_xor(s, o, 64);
    float alpha = ex / s;

    DRAIN16(wn_u);
    HOLD16(wm_u);

    float fr = 0.f, frm = 0.f, beta = 0.f;
#pragma unroll
    for (int k = 0; k < K_NB; ++k) {
        float ak = readlane_f(alpha, k);
        fr  += ak * bf2f(wn_u[k]);         // lanes 9..15 read record pad zeros
        frm += ak * bf2f(wm_u[k]);         // lanes >= ADIM garbage, never read
        beta += (readlane_i(kidx, k) > 0) ? ak : 0.f;
    }
    float acc = c2[lane] + beta * c3[lane];
#pragma unroll
    for (int j = 0; j < FDIM; ++j) acc += readlane_f(fr, j) * W3[j * H + lane];
#pragma unroll
    for (int j = 0; j < ADIM; ++j) acc += readlane_f(frm, j) * W2[j * H + lane];
    float o = (acc > 0.f) ? acc : expm1f(acc);   // elu
    hp2bf[(size_t)(n + 1) * H + lane] = f2bf(o);
    float ta = o * va[lane], tb = o * vb[lane];  // f32-exact logit scalars
#pragma unroll
    for (int q = 32; q > 0; q >>= 1) {
        ta += __shfl_xor(ta, q, 64);
        tb += __shfl_xor(tb, q, 64);
    }
    if (lane == 0) { t1B[n + 1] = ta; t2B[n + 1] = tb; }
}

// ---------------------------------------------------------------------------
// GAT iter 2 — fused gather + MFMA projection (round-0 structure).
// ROUND-7 CHANGE: pair-packed gathers. Each 64-lane dword gather reads TWO
// 128B rows (lanes 0-31 -> row kidx[g], lanes 32-63 -> row kidx[g+8];
// per-lane voff = row*128 + (lane&31)*4). 32 row-gathers -> 16 instructions.
// Theory: gather kernels are bound by VMEM address processing (~16cy per
// 64-lane instr/CU, measured 15.9 R0 / 14.8 gat1); halving instructions
// at equal VALU (readlane+cndmask addressing, NO shfl redistribution --
// round-1's mistake) should cut k_gat2 ~47 -> ~30us. Per-lane accumulation
// keeps 2 cols/lane over 8 rows; one shfl_xor(32) x4 merges halves; lanes
// 0-31 write the IDENTICAL s_rows layout the verified MFMA phase reads.
// ---------------------------------------------------------------------------
__global__ __launch_bounds__(1024) void k_gat2(
    const int* __restrict__ sse, const int* __restrict__ bsc,
    const int* __restrict__ sue,
    const float* __restrict__ t1B, const float* __restrict__ t2B,
    const unsigned short* __restrict__ hp2bf,
    const unsigned short* __restrict__ WintT,
    float* __restrict__ hp3)
{
    __shared__ unsigned s_rows[16][72];    // 16 rows x 64 uints (stride 72)
    int wave = threadIdx.x >> 6;           // 0..15 = row within block
    int lane = threadIdx.x & 63;
    int row  = blockIdx.x * 16 + wave;     // hp3 row
    int n    = row - 1;                    // node index (row 0 = pad)

    float gn0 = 0.f, gn1 = 0.f, gm0 = 0.f, gm1 = 0.f;
    if (n >= 0 && n < N_NODES) {
        int kidx = 0, ksu = 0;
        float lg = NEG_INF_F;
        if (lane < K_NB) {
            kidx = sse[n * K_NB + lane];
            int ke = bsc[n * K_NB + lane];
            ksu = sue[ke];                 // row 0 = zero row for masked edges
            float p = t1B[kidx] + t2B[ksu];
            p = (p > 0.f) ? p : 0.2f * p;
            lg = (kidx == 0) ? NEG_INF_F : p;
        }

        // Pair-packed gathers: instr g covers rows {kidx[g], kidx[g+8]}.
        int halfsel = lane >> 5;           // 0: low rows g, 1: high rows g+8
        int cbyte = (lane & 31) * 4;       // dword (col pair) within 128B row
        unsigned wp[16];                   // [0..7]=wn pairs, [8..15]=wm pairs
#pragma unroll
        for (int g = 0; g < 8; ++g) {
            int rA = readlane_i(kidx, g);
            int rB = readlane_i(kidx, g + 8);
            int r  = halfsel ? rB : rA;
            GLOAD_DW(wp[g], r * 128 + cbyte, hp2bf);
        }
#pragma unroll
        for (int g = 0; g < 8; ++g) {
            int sA = readlane_i(ksu, g);
            int sB = readlane_i(ksu, g + 8);
            int rs = halfsel ? sB : sA;
            GLOAD_DW(wp[8 + g], rs * 128 + cbyte, hp2bf);
        }

        // softmax across the 16-lane group — overlaps the in-flight gathers
        float m = lg;
#pragma unroll
        for (int o = 8; o > 0; o >>= 1) m = fmaxf(m, __shfl_xor(m, o, 64));
        float ex = __expf(lg - m);
        float s = ex;
#pragma unroll
        for (int o = 8; o > 0; o >>= 1) s += __shfl_xor(s, o, 64);
        float alpha = ex / s;

        DRAIN16(wp);

#pragma unroll
        for (int g = 0; g < 8; ++g) {
            float aA = readlane_f(alpha, g);
            float aB = readlane_f(alpha, g + 8);
            float av = halfsel ? aB : aA;  // weight for this lane's row
            unsigned wn = wp[g], wm = wp[8 + g];
            gn0 += av * bf2f(wn & 0xffffu);
            gn1 += av * bf2f(wn >> 16);
            gm0 += av * bf2f(wm & 0xffffu);
            gm1 += av * bf2f(wm >> 16);
        }
        // merge low-half (rows 0-7) and high-half (rows 8-15) partials
        gn0 += __shfl_xor(gn0, 32, 64);
        gn1 += __shfl_xor(gn1, 32, 64);
        gm0 += __shfl_xor(gm0, 32, 64);
        gm1 += __shfl_xor(gm1, 32, 64);
    }
    if (lane < 32) {                       // lane c holds cols 2c, 2c+1
        s_rows[wave][2 * lane]     = (unsigned)f2bf(gn0) | ((unsigned)f2bf(gm0) << 16);
        s_rows[wave][2 * lane + 1] = (unsigned)f2bf(gn1) | ((unsigned)f2bf(gm1) << 16);
    }
    __syncthreads();

    if (wave < 4) {                        // wave t = column strip t*16..
        int t = wave;
        int m = lane & 15, q = lane >> 4;
        union UB { uint4 u; bf16x8 v; };
        bf16x8 bfr[4];
        const unsigned short* bp = WintT + (size_t)(t * 16 + m) * 128 + q * 8;
#pragma unroll
        for (int kk = 0; kk < 4; ++kk) {
            UB ub; ub.u = *(const uint4*)(bp + kk * 32);
            bfr[kk] = ub.v;
        }
        f32x4 acc = (f32x4){0.f, 0.f, 0.f, 0.f};
#pragma unroll
        for (int kk = 0; kk < 4; ++kk) {
            UB ua; ua.u = *(const uint4*)&s_rows[m][kk * 16 + q * 4];
            acc = __builtin_amdgcn_mfma_f32_16x16x32_bf16(ua.v, bfr[kk], acc, 0, 0, 0);
        }
        int row0 = blockIdx.x * 16;
#pragma unroll
        for (int r = 0; r < 4; ++r) {
            int rr = row0 + q * 4 + r;
            if (rr <= N_NODES) {
                float v = acc[r];
                hp3[(size_t)rr * H + t * 16 + m] = (v > 0.f) ? v : expm1f(v);
            }
        }
    }
}

// ---------------------------------------------------------------------------
// out[b] = sum_m hp3[l_scope[b,m]] — 48 raw asm gathers all in flight.
// ---------------------------------------------------------------------------
__global__ __launch_bounds__(256) void k_out(
    const int* __restrict__ l_scope, const float* __restrict__ hp,
    float* __restrict__ out)
{
    int wave = threadIdx.x >> 6;
    int lane = threadIdx.x & 63;
    int b = blockIdx.x * 4 + wave;
    if (b >= B_MOL) return;
    int idx48 = (lane < MAXM_M) ? l_scope[b * MAXM_M + lane] : 0;
    float v[MAXM_M];
    int off = lane * 4;
#pragma unroll
    for (int m = 0; m < MAXM_M; ++m) {
        const float* pm = hp + (size_t)readlane_i(idx48, m) * H;
        GLOAD_F32(v[m], off, pm);
    }
    asm volatile("s_waitcnt vmcnt(0)"
        : "+v"(v[0]), "+v"(v[1]), "+v"(v[2]), "+v"(v[3]),
          "+v"(v[4]), "+v"(v[5]), "+v"(v[6]), "+v"(v[7]),
          "+v"(v[8]), "+v"(v[9]), "+v"(v[10]), "+v"(v[11]),
          "+v"(v[12]), "+v"(v[13]), "+v"(v[14]), "+v"(v[15]));
    asm volatile(""
        : "+v"(v[16]), "+v"(v[17]), "+v"(v[18]), "+v"(v[19]),
          "+v"(v[20]), "+v"(v[21]), "+v"(v[22]), "+v"(v[23]),
          "+v"(v[24]), "+v"(v[25]), "+v"(v[26]), "+v"(v[27]),
          "+v"(v[28]), "+v"(v[29]), "+v"(v[30]), "+v"(v[31]));
    asm volatile(""
        : "+v"(v[32]), "+v"(v[33]), "+v"(v[34]), "+v"(v[35]),
          "+v"(v[36]), "+v"(v[37]), "+v"(v[38]), "+v"(v[39]),
          "+v"(v[40]), "+v"(v[41]), "+v"(v[42]), "+v"(v[43]),
          "+v"(v[44]), "+v"(v[45]), "+v"(v[46]), "+v"(v[47]));
    float acc = 0.f;
#pragma unroll
    for (int m = 0; m < MAXM_M; ++m) acc += v[m];
    out[b * H + lane] = acc;
}

extern "C" void kernel_launch(void* const* d_in, const int* in_sizes, int n_in,
                              void* d_out, int out_size, void* d_ws, size_t ws_size,
                              hipStream_t stream)
{
    const float* tf     = (const float*)d_in[0];
    const float* fdg    = (const float*)d_in[1];
    const float* rij    = (const float*)d_in[2];
    const int*   sse    = (const int*)d_in[3];
    const int*   bsc    = (const int*)d_in[4];
    const int*   lsc    = (const int*)d_in[5];
    const int*   su     = (const int*)d_in[6];
    const int*   sul    = (const int*)d_in[7];
    const float* W_emb  = (const float*)d_in[8];
    const float* b_emb  = (const float*)d_in[9];
    const float* W_dist = (const float*)d_in[10];
    const float* b_dist = (const float*)d_in[11];
    const float* W_gat  = (const float*)d_in[12];
    const float* Wm_gat = (const float*)d_in[13];
    const float* a_gat  = (const float*)d_in[14];
    float* out = (float*)d_out;

    char* base = (char*)d_ws;
    size_t off = 0;
    auto alloc = [&](size_t bytes) {
        char* p = base + off;
        off = (off + bytes + 255) & ~(size_t)255;
        return p;
    };
    float* W2   = (float*)alloc(640 * 4);
    float* c2   = (float*)alloc(64 * 4);
    float* W3   = (float*)alloc(640 * 4);
    float* c3   = (float*)alloc(64 * 4);
    float* wa   = (float*)alloc(16 * 4);
    float* ca   = (float*)alloc(16 * 4);
    float* va   = (float*)alloc(64 * 4);
    float* vb   = (float*)alloc(64 * 4);
    float* wv9  = (float*)alloc(16 * 4);
    float* cv   = (float*)alloc(16 * 4);
    unsigned short* WintT = (unsigned short*)alloc(64 * 128 * 2);
    float* t1A  = (float*)alloc((size_t)(N_NODES + 1) * 4);
    float* t1B  = (float*)alloc((size_t)(N_NODES + 1) * 4);
    float* t2B  = (float*)alloc((size_t)(N_NODES + 1) * 4);
    int*   sue  = (int*)alloc((size_t)E_EDGES * 4);
    unsigned short* tfp   = (unsigned short*)alloc((size_t)(N_NODES + 1) * 16 * 2);
    unsigned short* hp2bf = (unsigned short*)alloc((size_t)(N_NODES + 1) * H * 2);
    // emsg (25.6MB) and hp3 (12.8MB) alias: emsg dead before k_gat2 writes hp3
    char* big = alloc((size_t)E_EDGES * 32);
    unsigned short* emsg = (unsigned short*)big;
    float* hp3 = (float*)big;

    k_fold<<<dim3(1), dim3(256), 0, stream>>>(
        W_emb, b_emb, W_dist, b_dist, W_gat, Wm_gat, a_gat,
        W2, c2, W3, c3, wa, ca, va, vb, wv9, cv, WintT);

    k_pre<<<dim3(PRE_NODE_BLOCKS + EDGE_BLOCKS), dim3(256), 0, stream>>>(
        tf, fdg, rij, su, sul, wa, ca, wv9, cv, t1A, tfp, emsg, sue);

    k_gat1<<<dim3((N_NODES + 3) / 4), dim3(256), 0, stream>>>(
        sse, bsc, t1A, tfp, emsg, W2, c2, W3, c3, va, vb, hp2bf, t1B, t2B);

    k_gat2<<<dim3((N_NODES + 16) / 16), dim3(1024), 0, stream>>>(
        sse, bsc, sue, t1B, t2B, hp2bf, WintT, hp3);

    k_out<<<dim3(B_MOL / 4), dim3(256), 0, stream>>>(lsc, hp3, out);
}

// Round 8
// 201.566 us; speedup vs baseline: 1.2877x; 1.0328x over previous
//
#include <hip/hip_runtime.h>
#include <hip/hip_bf16.h>

#define N_NODES 50000
#define K_NB 16
#define E_EDGES 800000
#define B_MOL 1024
#define MAXM_M 48
#define FDIM 9
#define ADIM 10
#define H 64
#define NEG_INF_F (-1e9f)
#define PRE_NODE_BLOCKS 196  /* 1 thread per node */
#define EDGE_BLOCKS 3125     /* 256 edges per block */

typedef __bf16 bf16x8 __attribute__((ext_vector_type(8)));
typedef float f32x4 __attribute__((ext_vector_type(4)));

__device__ inline float readlane_f(float v, int l) {
    return __int_as_float(__builtin_amdgcn_readlane(__float_as_int(v), l));
}
__device__ inline int readlane_i(int v, int l) {
    return __builtin_amdgcn_readlane(v, l);
}
__device__ inline float bf2f(unsigned u) {         // u = zero-extended bf16
    return __uint_as_float(u << 16);
}
__device__ inline unsigned short f2bf(float f) {   // round-to-nearest-even
    unsigned x = __float_as_uint(f);
    return (unsigned short)((x + 0x7fffu + ((x >> 16) & 1u)) >> 16);
}

// Raw gather, wave-uniform SGPR base + per-lane VGPR byte offset.
#define GLOAD_U16(dst, voff, sbase) \
    asm volatile("global_load_ushort %0, %1, %2" : "=v"(dst) : "v"(voff), "s"(sbase))
#define GLOAD_F32(dst, voff, sbase) \
    asm volatile("global_load_dword %0, %1, %2" : "=v"(dst) : "v"(voff), "s"(sbase))
#define GLOAD_DW(dst, voff, sbase) \
    asm volatile("global_load_dword %0, %1, %2" : "=v"(dst) : "v"(voff), "s"(sbase))

#define DRAIN16(a) \
    asm volatile("s_waitcnt vmcnt(0)" \
        : "+v"(a[0]), "+v"(a[1]), "+v"(a[2]), "+v"(a[3]), \
          "+v"(a[4]), "+v"(a[5]), "+v"(a[6]), "+v"(a[7]), \
          "+v"(a[8]), "+v"(a[9]), "+v"(a[10]), "+v"(a[11]), \
          "+v"(a[12]), "+v"(a[13]), "+v"(a[14]), "+v"(a[15]))
#define DRAIN8(a, b) \
    asm volatile("s_waitcnt vmcnt(0)" \
        : "+v"(a[0]), "+v"(a[1]), "+v"(a[2]), "+v"(a[3]), \
          "+v"(b[0]), "+v"(b[1]), "+v"(b[2]), "+v"(b[3]))

// ---------------------------------------------------------------------------
// Fold all weight algebra (single block):
//   va/vb, W2/c2, W3/c3, wa/ca, wv9/cv, plus
//   WintT[64][128] bf16: WintT[n][2j]=W_gat[j][n], WintT[n][2j+1]=Wm_gat[j][n]
// ---------------------------------------------------------------------------
__global__ __launch_bounds__(256) void k_fold(
    const float* __restrict__ W_emb, const float* __restrict__ b_emb,
    const float* __restrict__ W_dist, const float* __restrict__ b_dist,
    const float* __restrict__ W_gat, const float* __restrict__ Wm_gat,
    const float* __restrict__ a_gat,
    float* __restrict__ W2, float* __restrict__ c2,
    float* __restrict__ W3, float* __restrict__ c3,
    float* __restrict__ wa, float* __restrict__ ca,
    float* __restrict__ va, float* __restrict__ vb,
    float* __restrict__ wv9, float* __restrict__ cv,
    unsigned short* __restrict__ WintT)
{
    __shared__ float s_va[64], s_vb[64];
    int tid = threadIdx.x;
    int h = tid & 63, g = tid >> 6;
    if (g == 0) {            // va[h] = W_gat[h,:] . a1
        float acc = 0.f;
        for (int t = 0; t < H; ++t) acc += W_gat[h * H + t] * a_gat[t];
        s_va[h] = acc; va[h] = acc;
    } else if (g == 1) {     // vb[h] = Wm_gat[h,:] . a2
        float acc = 0.f;
        for (int t = 0; t < H; ++t) acc += Wm_gat[h * H + t] * a_gat[H + t];
        s_vb[h] = acc; vb[h] = acc;
    } else if (g == 2) {     // c2
        float acc = 0.f;
        for (int t = 0; t < H; ++t) acc += b_dist[t] * Wm_gat[t * H + h];
        c2[h] = acc;
    } else {                 // c3
        float acc = 0.f;
        for (int t = 0; t < H; ++t) acc += b_emb[t] * W_gat[t * H + h];
        c3[h] = acc;
    }
    __syncthreads();
    for (int q = tid; q < 640; q += 256) {   // W2[j,h]
        int j = q >> 6, hh = q & 63;
        float acc = 0.f;
        for (int t = 0; t < H; ++t) acc += W_dist[j * H + t] * Wm_gat[t * H + hh];
        W2[q] = acc;
    }
    for (int q = tid; q < 576; q += 256) {   // W3[j,h]
        int j = q >> 6, hh = q & 63;
        float acc = 0.f;
        for (int t = 0; t < H; ++t) acc += W_emb[j * H + t] * W_gat[t * H + hh];
        W3[q] = acc;
    }
    for (int q = tid; q < H * 2 * H; q += 256) {  // WintT[n][k], 8192 entries
        int n = q >> 7, k = q & 127;
        float v = (k & 1) ? Wm_gat[(k >> 1) * H + n] : W_gat[(k >> 1) * H + n];
        WintT[q] = f2bf(v);
    }
    if (tid < ADIM) {                         // wa
        float acc = 0.f;
        for (int t = 0; t < H; ++t) acc += W_dist[tid * H + t] * s_vb[t];
        wa[tid] = acc;
    } else if (tid == ADIM) {                 // ca
        float acc = 0.f;
        for (int t = 0; t < H; ++t) acc += b_dist[t] * s_vb[t];
        ca[0] = acc;
    } else if (tid >= 16 && tid < 16 + FDIM) {// wv9
        int j = tid - 16;
        float acc = 0.f;
        for (int t = 0; t < H; ++t) acc += W_emb[j * H + t] * s_va[t];
        wv9[j] = acc;
    } else if (tid == 31) {                   // cv
        float acc = 0.f;
        for (int t = 0; t < H; ++t) acc += b_emb[t] * s_va[t];
        cv[0] = acc;
    }
}

// ---------------------------------------------------------------------------
// Pre-pass: t1A + tfp records (node side); emsg records + sue (edge side).
// ---------------------------------------------------------------------------
__global__ __launch_bounds__(256) void k_pre(
    const float* __restrict__ tf, const float* __restrict__ fdg,
    const float* __restrict__ rij,
    const int* __restrict__ su, const int* __restrict__ sul,
    const float* __restrict__ wa, const float* __restrict__ ca,
    const float* __restrict__ wv9, const float* __restrict__ cv,
    float* __restrict__ t1A, unsigned short* __restrict__ tfp,
    unsigned short* __restrict__ emsg, int* __restrict__ sue)
{
    int bid = blockIdx.x;
    if (bid < PRE_NODE_BLOCKS) {
        int n = bid * 256 + threadIdx.x;
        if (n == 0) {                        // zero pad row
            t1A[0] = 0.f;
            uint4 z = make_uint4(0, 0, 0, 0);
            ((uint4*)tfp)[0] = z; ((uint4*)tfp)[1] = z;
        }
        if (n >= N_NODES) return;
        float f[FDIM];
        float acc = cv[0];
#pragma unroll
        for (int j = 0; j < FDIM; ++j) {
            f[j] = tf[n * FDIM + j];
            acc += f[j] * wv9[j];
        }
        t1A[n + 1] = acc;
        unsigned rec[8];
#pragma unroll
        for (int j = 0; j < 4; ++j)
            rec[j] = (unsigned)f2bf(f[2 * j]) | ((unsigned)f2bf(f[2 * j + 1]) << 16);
        rec[4] = (unsigned)f2bf(f[8]);
        rec[5] = 0; rec[6] = 0; rec[7] = 0;
        uint4* dst = (uint4*)(tfp + (size_t)(n + 1) * 16);
        dst[0] = make_uint4(rec[0], rec[1], rec[2], rec[3]);
        dst[1] = make_uint4(rec[4], rec[5], rec[6], rec[7]);
    } else {
        int e = (bid - PRE_NODE_BLOCKS) * 256 + threadIdx.x;
        float f[ADIM];
#pragma unroll
        for (int j = 0; j < FDIM; ++j) f[j] = fdg[(size_t)e * FDIM + j];
        f[FDIM] = rij[e];
        float acc = ca[0];
#pragma unroll
        for (int j = 0; j < ADIM; ++j) acc += f[j] * wa[j];
        unsigned rec[8];
#pragma unroll
        for (int j = 0; j < 5; ++j)
            rec[j] = (unsigned)f2bf(f[2 * j]) | ((unsigned)f2bf(f[2 * j + 1]) << 16);
        rec[5] = __float_as_uint(acc);
        rec[6] = 0; rec[7] = 0;
        uint4* dst = (uint4*)(emsg + (size_t)e * 16);
        dst[0] = make_uint4(rec[0], rec[1], rec[2], rec[3]);
        dst[1] = make_uint4(rec[4], rec[5], rec[6], rec[7]);
        sue[e] = (sul[e] > 0) ? su[e] : 0;
    }
}

// ---------------------------------------------------------------------------
// GAT iter 1 — ROUND-8: quad-packed gathers. Records are 32B and the old
// code used 64 lanes with (lane&15)*2 offsets = 4x lane redundancy. Now
// instr g reads FOUR records {kidx[g],kidx[g+4],kidx[g+8],kidx[g+12]}:
// quadrant q=lane>>4 selects its record via 3 cndmask (no LDS routing).
// 32 record-gathers -> 8 instructions. Quadrant partials merge with two
// shfl_xor; epilogue (readlane projection) unchanged — every lane holds
// the full fr/frm sum, element (lane&15).
// ---------------------------------------------------------------------------
__global__ __launch_bounds__(256) void k_gat1(
    const int* __restrict__ sse, const int* __restrict__ bsc,
    const float* __restrict__ t1A, const unsigned short* __restrict__ tfp,
    const unsigned short* __restrict__ emsg,
    const float* __restrict__ W2, const float* __restrict__ c2,
    const float* __restrict__ W3, const float* __restrict__ c3,
    const float* __restrict__ va, const float* __restrict__ vb,
    unsigned short* __restrict__ hp2bf, float* __restrict__ t1B,
    float* __restrict__ t2B)
{
    int wave = threadIdx.x >> 6;
    int lane = threadIdx.x & 63;
    int n = blockIdx.x * 4 + wave;
    if (n == 0) {
        hp2bf[lane] = 0;
        if (lane == 0) { t1B[0] = 0.f; t2B[0] = 0.f; }
    }
    if (n >= N_NODES) return;

    int kidx = 0, ke = 0;
    float lg = NEG_INF_F;
    if (lane < K_NB) {
        kidx = sse[n * K_NB + lane];
        ke   = bsc[n * K_NB + lane];
        float g2 = __uint_as_float(*(const unsigned*)(emsg + (size_t)ke * 16 + 10));
        float p = t1A[kidx] + g2;
        p = (p > 0.f) ? p : 0.2f * p;      // leaky_relu(0.2)
        lg = (kidx == 0) ? NEG_INF_F : p;  // pad mask
    }

    // quad-packed gathers: instr g covers records {g, g+4, g+8, g+12}
    int q1 = lane & 16;                    // quadrant bit0 (as mask)
    int q2 = lane & 32;                    // quadrant bit1 (as mask)
    int elem2 = (lane & 15) * 2;           // short offset within 32B record
    unsigned wn_u[4], wm_u[4];
#pragma unroll
    for (int g = 0; g < 4; ++g) {
        int rA = readlane_i(kidx, g);
        int rB = readlane_i(kidx, g + 4);
        int rC = readlane_i(kidx, g + 8);
        int rD = readlane_i(kidx, g + 12);
        int rLo = q1 ? rB : rA;
        int rHi = q1 ? rD : rC;
        int r   = q2 ? rHi : rLo;
        GLOAD_U16(wn_u[g], r * 32 + elem2, tfp);
    }
#pragma unroll
    for (int g = 0; g < 4; ++g) {
        int rA = readlane_i(ke, g);
        int rB = readlane_i(ke, g + 4);
        int rC = readlane_i(ke, g + 8);
        int rD = readlane_i(ke, g + 12);
        int rLo = q1 ? rB : rA;
        int rHi = q1 ? rD : rC;
        int r   = q2 ? rHi : rLo;
        GLOAD_U16(wm_u[g], r * 32 + elem2, emsg);
    }

    // softmax across the 16-lane group — overlaps the gathers
    float m = lg;
#pragma unroll
    for (int o = 8; o > 0; o >>= 1) m = fmaxf(m, __shfl_xor(m, o, 64));
    float ex = __expf(lg - m);
    float s = ex;
#pragma unroll
    for (int o = 8; o > 0; o >>= 1) s += __shfl_xor(s, o, 64);
    float alpha = ex / s;

    // beta via full butterfly: lanes>=16 have kidx==0 -> contribute 0
    float beta = (kidx > 0) ? alpha : 0.f;
#pragma unroll
    for (int o = 1; o <= 32; o <<= 1) beta += __shfl_xor(beta, o, 64);

    DRAIN8(wn_u, wm_u);

    float fr = 0.f, frm = 0.f;
#pragma unroll
    for (int g = 0; g < 4; ++g) {
        float aA = readlane_f(alpha, g);
        float aB = readlane_f(alpha, g + 4);
        float aC = readlane_f(alpha, g + 8);
        float aD = readlane_f(alpha, g + 12);
        float aLo = q1 ? aB : aA;
        float aHi = q1 ? aD : aC;
        float av  = q2 ? aHi : aLo;
        fr  += av * bf2f(wn_u[g]);         // lanes 9..15 read record pad zeros
        frm += av * bf2f(wm_u[g]);         // elems >= ADIM garbage, never read
    }
    fr  += __shfl_xor(fr, 16, 64);  fr  += __shfl_xor(fr, 32, 64);
    frm += __shfl_xor(frm, 16, 64); frm += __shfl_xor(frm, 32, 64);

    float acc = c2[lane] + beta * c3[lane];
#pragma unroll
    for (int j = 0; j < FDIM; ++j) acc += readlane_f(fr, j) * W3[j * H + lane];
#pragma unroll
    for (int j = 0; j < ADIM; ++j) acc += readlane_f(frm, j) * W2[j * H + lane];
    float o = (acc > 0.f) ? acc : expm1f(acc);   // elu
    hp2bf[(size_t)(n + 1) * H + lane] = f2bf(o);
    float ta = o * va[lane], tb = o * vb[lane];  // f32-exact logit scalars
#pragma unroll
    for (int q = 32; q > 0; q >>= 1) {
        ta += __shfl_xor(ta, q, 64);
        tb += __shfl_xor(tb, q, 64);
    }
    if (lane == 0) { t1B[n + 1] = ta; t2B[n + 1] = tb; }
}

// ---------------------------------------------------------------------------
// GAT iter 2 — ROUND-8: 512-thread blocks (8 rows) for latency overlap.
// 1024-thread blocks capped concurrency at 2 blocks/CU and one barrier
// coupled 16 waves to the slowest gather (Occ 59%). 8-row blocks give
// 4 blocks/CU (32 waves = 100%) and half-size barrier groups. The verified
// 16x16 MFMA phase is kept: upper 8 A-rows zeroed, stores guarded to the
// block's 8 rows. Gather = round-7 pair-packed form (proven, 44.5us).
// ---------------------------------------------------------------------------
__global__ __launch_bounds__(512) void k_gat2(
    const int* __restrict__ sse, const int* __restrict__ bsc,
    const int* __restrict__ sue,
    const float* __restrict__ t1B, const float* __restrict__ t2B,
    const unsigned short* __restrict__ hp2bf,
    const unsigned short* __restrict__ WintT,
    float* __restrict__ hp3)
{
    __shared__ unsigned s_rows[16][72];    // 16 rows x 64 uints (stride 72)
    int wave = threadIdx.x >> 6;           // 0..7 = row within block
    int lane = threadIdx.x & 63;
    int row  = blockIdx.x * 8 + wave;      // hp3 row
    int n    = row - 1;                    // node index (row 0 = pad)

    // zero the unused upper 8 A-rows (MFMA garbage guard, written once)
    if (lane < 32) {
        s_rows[wave + 8][2 * lane]     = 0u;
        s_rows[wave + 8][2 * lane + 1] = 0u;
    }

    float gn0 = 0.f, gn1 = 0.f, gm0 = 0.f, gm1 = 0.f;
    if (n >= 0 && n < N_NODES) {
        int kidx = 0, ksu = 0;
        float lg = NEG_INF_F;
        if (lane < K_NB) {
            kidx = sse[n * K_NB + lane];
            int ke = bsc[n * K_NB + lane];
            ksu = sue[ke];                 // row 0 = zero row for masked edges
            float p = t1B[kidx] + t2B[ksu];
            p = (p > 0.f) ? p : 0.2f * p;
            lg = (kidx == 0) ? NEG_INF_F : p;
        }

        // Pair-packed gathers: instr g covers rows {kidx[g], kidx[g+8]}.
        int halfsel = lane >> 5;           // 0: low rows g, 1: high rows g+8
        int cbyte = (lane & 31) * 4;       // dword (col pair) within 128B row
        unsigned wp[16];                   // [0..7]=wn pairs, [8..15]=wm pairs
#pragma unroll
        for (int g = 0; g < 8; ++g) {
            int rA = readlane_i(kidx, g);
            int rB = readlane_i(kidx, g + 8);
            int r  = halfsel ? rB : rA;
            GLOAD_DW(wp[g], r * 128 + cbyte, hp2bf);
        }
#pragma unroll
        for (int g = 0; g < 8; ++g) {
            int sA = readlane_i(ksu, g);
            int sB = readlane_i(ksu, g + 8);
            int rs = halfsel ? sB : sA;
            GLOAD_DW(wp[8 + g], rs * 128 + cbyte, hp2bf);
        }

        // softmax across the 16-lane group — overlaps the in-flight gathers
        float m = lg;
#pragma unroll
        for (int o = 8; o > 0; o >>= 1) m = fmaxf(m, __shfl_xor(m, o, 64));
        float ex = __expf(lg - m);
        float s = ex;
#pragma unroll
        for (int o = 8; o > 0; o >>= 1) s += __shfl_xor(s, o, 64);
        float alpha = ex / s;

        DRAIN16(wp);

#pragma unroll
        for (int g = 0; g < 8; ++g) {
            float aA = readlane_f(alpha, g);
            float aB = readlane_f(alpha, g + 8);
            float av = halfsel ? aB : aA;  // weight for this lane's row
            unsigned wn = wp[g], wm = wp[8 + g];
            gn0 += av * bf2f(wn & 0xffffu);
            gn1 += av * bf2f(wn >> 16);
            gm0 += av * bf2f(wm & 0xffffu);
            gm1 += av * bf2f(wm >> 16);
        }
        // merge low-half (rows 0-7) and high-half (rows 8-15) partials
        gn0 += __shfl_xor(gn0, 32, 64);
        gn1 += __shfl_xor(gn1, 32, 64);
        gm0 += __shfl_xor(gm0, 32, 64);
        gm1 += __shfl_xor(gm1, 32, 64);
    }
    if (lane < 32) {                       // lane c holds cols 2c, 2c+1
        s_rows[wave][2 * lane]     = (unsigned)f2bf(gn0) | ((unsigned)f2bf(gm0) << 16);
        s_rows[wave][2 * lane + 1] = (unsigned)f2bf(gn1) | ((unsigned)f2bf(gm1) << 16);
    }
    __syncthreads();

    if (wave < 4) {                        // wave t = column strip t*16..
        int t = wave;
        int m = lane & 15, q = lane >> 4;
        union UB { uint4 u; bf16x8 v; };
        bf16x8 bfr[4];
        const unsigned short* bp = WintT + (size_t)(t * 16 + m) * 128 + q * 8;
#pragma unroll
        for (int kk = 0; kk < 4; ++kk) {
            UB ub; ub.u = *(const uint4*)(bp + kk * 32);
            bfr[kk] = ub.v;
        }
        f32x4 acc = (f32x4){0.f, 0.f, 0.f, 0.f};
#pragma unroll
        for (int kk = 0; kk < 4; ++kk) {
            UB ua; ua.u = *(const uint4*)&s_rows[m][kk * 16 + q * 4];
            acc = __builtin_amdgcn_mfma_f32_16x16x32_bf16(ua.v, bfr[kk], acc, 0, 0, 0);
        }
        int row0 = blockIdx.x * 8;
        if (q < 2) {                       // D rows 0-7 only (8-15 = garbage)
#pragma unroll
            for (int r = 0; r < 4; ++r) {
                int rr = row0 + q * 4 + r;
                if (rr <= N_NODES) {
                    float v = acc[r];
                    hp3[(size_t)rr * H + t * 16 + m] = (v > 0.f) ? v : expm1f(v);
                }
            }
        }
    }
}

// ---------------------------------------------------------------------------
// out[b] = sum_m hp3[l_scope[b,m]] — 48 raw asm gathers all in flight.
// ---------------------------------------------------------------------------
__global__ __launch_bounds__(256) void k_out(
    const int* __restrict__ l_scope, const float* __restrict__ hp,
    float* __restrict__ out)
{
    int wave = threadIdx.x >> 6;
    int lane = threadIdx.x & 63;
    int b = blockIdx.x * 4 + wave;
    if (b >= B_MOL) return;
    int idx48 = (lane < MAXM_M) ? l_scope[b * MAXM_M + lane] : 0;
    float v[MAXM_M];
    int off = lane * 4;
#pragma unroll
    for (int m = 0; m < MAXM_M; ++m) {
        const float* pm = hp + (size_t)readlane_i(idx48, m) * H;
        GLOAD_F32(v[m], off, pm);
    }
    asm volatile("s_waitcnt vmcnt(0)"
        : "+v"(v[0]), "+v"(v[1]), "+v"(v[2]), "+v"(v[3]),
          "+v"(v[4]), "+v"(v[5]), "+v"(v[6]), "+v"(v[7]),
          "+v"(v[8]), "+v"(v[9]), "+v"(v[10]), "+v"(v[11]),
          "+v"(v[12]), "+v"(v[13]), "+v"(v[14]), "+v"(v[15]));
    asm volatile(""
        : "+v"(v[16]), "+v"(v[17]), "+v"(v[18]), "+v"(v[19]),
          "+v"(v[20]), "+v"(v[21]), "+v"(v[22]), "+v"(v[23]),
          "+v"(v[24]), "+v"(v[25]), "+v"(v[26]), "+v"(v[27]),
          "+v"(v[28]), "+v"(v[29]), "+v"(v[30]), "+v"(v[31]));
    asm volatile(""
        : "+v"(v[32]), "+v"(v[33]), "+v"(v[34]), "+v"(v[35]),
          "+v"(v[36]), "+v"(v[37]), "+v"(v[38]), "+v"(v[39]),
          "+v"(v[40]), "+v"(v[41]), "+v"(v[42]), "+v"(v[43]),
          "+v"(v[44]), "+v"(v[45]), "+v"(v[46]), "+v"(v[47]));
    float acc = 0.f;
#pragma unroll
    for (int m = 0; m < MAXM_M; ++m) acc += v[m];
    out[b * H + lane] = acc;
}

extern "C" void kernel_launch(void* const* d_in, const int* in_sizes, int n_in,
                              void* d_out, int out_size, void* d_ws, size_t ws_size,
                              hipStream_t stream)
{
    const float* tf     = (const float*)d_in[0];
    const float* fdg    = (const float*)d_in[1];
    const float* rij    = (const float*)d_in[2];
    const int*   sse    = (const int*)d_in[3];
    const int*   bsc    = (const int*)d_in[4];
    const int*   lsc    = (const int*)d_in[5];
    const int*   su     = (const int*)d_in[6];
    const int*   sul    = (const int*)d_in[7];
    const float* W_emb  = (const float*)d_in[8];
    const float* b_emb  = (const float*)d_in[9];
    const float* W_dist = (const float*)d_in[10];
    const float* b_dist = (const float*)d_in[11];
    const float* W_gat  = (const float*)d_in[12];
    const float* Wm_gat = (const float*)d_in[13];
    const float* a_gat  = (const float*)d_in[14];
    float* out = (float*)d_out;

    char* base = (char*)d_ws;
    size_t off = 0;
    auto alloc = [&](size_t bytes) {
        char* p = base + off;
        off = (off + bytes + 255) & ~(size_t)255;
        return p;
    };
    float* W2   = (float*)alloc(640 * 4);
    float* c2   = (float*)alloc(64 * 4);
    float* W3   = (float*)alloc(640 * 4);
    float* c3   = (float*)alloc(64 * 4);
    float* wa   = (float*)alloc(16 * 4);
    float* ca   = (float*)alloc(16 * 4);
    float* va   = (float*)alloc(64 * 4);
    float* vb   = (float*)alloc(64 * 4);
    float* wv9  = (float*)alloc(16 * 4);
    float* cv   = (float*)alloc(16 * 4);
    unsigned short* WintT = (unsigned short*)alloc(64 * 128 * 2);
    float* t1A  = (float*)alloc((size_t)(N_NODES + 1) * 4);
    float* t1B  = (float*)alloc((size_t)(N_NODES + 1) * 4);
    float* t2B  = (float*)alloc((size_t)(N_NODES + 1) * 4);
    int*   sue  = (int*)alloc((size_t)E_EDGES * 4);
    unsigned short* tfp   = (unsigned short*)alloc((size_t)(N_NODES + 1) * 16 * 2);
    unsigned short* hp2bf = (unsigned short*)alloc((size_t)(N_NODES + 1) * H * 2);
    // emsg (25.6MB) and hp3 (12.8MB) alias: emsg dead before k_gat2 writes hp3
    char* big = alloc((size_t)E_EDGES * 32);
    unsigned short* emsg = (unsigned short*)big;
    float* hp3 = (float*)big;

    k_fold<<<dim3(1), dim3(256), 0, stream>>>(
        W_emb, b_emb, W_dist, b_dist, W_gat, Wm_gat, a_gat,
        W2, c2, W3, c3, wa, ca, va, vb, wv9, cv, WintT);

    k_pre<<<dim3(PRE_NODE_BLOCKS + EDGE_BLOCKS), dim3(256), 0, stream>>>(
        tf, fdg, rij, su, sul, wa, ca, wv9, cv, t1A, tfp, emsg, sue);

    k_gat1<<<dim3((N_NODES + 3) / 4), dim3(256), 0, stream>>>(
        sse, bsc, t1A, tfp, emsg, W2, c2, W3, c3, va, vb, hp2bf, t1B, t2B);

    k_gat2<<<dim3((N_NODES + 8) / 8), dim3(512), 0, stream>>>(
        sse, bsc, sue, t1B, t2B, hp2bf, WintT, hp3);

    k_out<<<dim3(B_MOL / 4), dim3(256), 0, stream>>>(lsc, hp3, out);
}